// Round 11
// baseline (110.426 us; speedup 1.0000x reference)
//
#include <hip/hip_runtime.h>
#include <hip/hip_bf16.h>

typedef float f32x4 __attribute__((ext_vector_type(4)));

#define NB 32      // batch
#define NT 2000    // time
#define NW 512     // width
#define NG 20      // groups (T / NUM_STEPS)
#define NS 100     // NUM_STEPS
#define NH 1024    // hidden
#define NO 10      // outputs
#define BETA 0.95f
#define THRESH 1.0f

// ------- Kernel 1 (fused): conv+scan1 blocks [0,1280) + transpose blocks [1280,1792) -------
// k1 part: ROUND-3 VERSION, marginal-measured ~78us (round 5) = HBM roofline. FROZEN.
// transpose block 0 also zeroes the k2 completion counter (stream-ordered before k2).
__global__ __launch_bounds__(256) void k1_conv_scan_tr(
    const f32x4* __restrict__ x,    // [B][T][W] of float4 (C=4 innermost)
    const float* __restrict__ cw,   // [4]
    const float* __restrict__ cb,   // [1]
    float* __restrict__ spk1,       // [B][G][W]
    const float* __restrict__ wsrc, // [H][W] hidden_w
    float* __restrict__ wT,         // [W][H]
    int* __restrict__ counter)
{
    __shared__ float tile[32][33];
    int bid = blockIdx.x;

    if (bid < 1280) {
        int half = bid & 1;             // which half of the 512-wide row
        int bg = bid >> 1;              // 0..639
        int g = bg % NG;
        int b = bg / NG;
        int tid = threadIdx.x;          // 0..255

        const f32x4* __restrict__ base =
            x + ((size_t)(b * NT + g * NS) * NW + half * 256);

        float w0 = cw[0], w1 = cw[1], w2 = cw[2], w3 = cw[3];
        float bias = cb[0];

        f32x4 A[10], B[10];
        float mem = 0.0f;

#define LOAD10(dst, S0)                                                        \
    {                                                                          \
        _Pragma("unroll")                                                      \
        for (int j = 0; j < 10; ++j)                                           \
            dst[j] = __builtin_nontemporal_load(base + (tid + ((S0) + j) * NW)); \
    }
#define STEP10(src)                                                            \
    {                                                                          \
        _Pragma("unroll")                                                      \
        for (int j = 0; j < 10; ++j) {                                         \
            f32x4 v = src[j];                                                  \
            float f = fmaf(v[0], w0, fmaf(v[1], w1,                            \
                      fmaf(v[2], w2, fmaf(v[3], w3, bias))));                  \
            float base_m = fmaf(BETA, mem, f);                                 \
            mem = (mem > THRESH) ? 0.0f : base_m;                              \
        }                                                                      \
    }

        LOAD10(A, 0)
        LOAD10(B, 10) STEP10(A)
        LOAD10(A, 20) STEP10(B)
        LOAD10(B, 30) STEP10(A)
        LOAD10(A, 40) STEP10(B)
        LOAD10(B, 50) STEP10(A)
        LOAD10(A, 60) STEP10(B)
        LOAD10(B, 70) STEP10(A)
        LOAD10(A, 80) STEP10(B)
        LOAD10(B, 90) STEP10(A)
        STEP10(B)
#undef LOAD10
#undef STEP10

        spk1[(b * NG + g) * NW + half * 256 + tid] = (mem > THRESH) ? 1.0f : 0.0f;
    } else {
        // transpose hidden_w (1024x512 -> 512x1024)
        int tbid = bid - 1280;           // 0..511
        if (tbid == 0 && threadIdx.x == 0) *counter = 0;   // reset k2 counter
        int bk = tbid & 15;              // 16 tiles over W
        int bh = tbid >> 4;              // 32 tiles over H
        int tx = threadIdx.x & 31;       // 0..31
        int ty = threadIdx.x >> 5;       // 0..7
        #pragma unroll
        for (int j = 0; j < 4; ++j)
            tile[ty + j * 8][tx] = wsrc[(bh * 32 + ty + j * 8) * NW + bk * 32 + tx];
        __syncthreads();
        #pragma unroll
        for (int j = 0; j < 4; ++j)
            wT[(bk * 32 + ty + j * 8) * NH + bh * 32 + tx] = tile[tx][ty + j * 8];
    }
}

// ---------------- Kernel 2 v6: hidden GEMM + scan2 + output + softmax -----------
// Round 9/10 isolated two independent wins never yet combined: h_pt=4 (halves
// per-wave ds_read count; v4) and 2 blocks/CU (latency overlap; v5). Both fit
// by ALIASING the reduction buffer onto sk (sk dead after GEMM) -> 40KB LDS.
// c = t>>4 gives 16 k-chunks of 32 kk; the 4 unique sk addrs/wave are 128B
// apart (same banks) -> fixed by rotating kkg order per chunk (conflict-free).
// Epilogue: wave0 scan + folded output dots; LAST block (threadfence+atomic
// counter) sums partials + softmax -> separate softmax kernel deleted.
__global__ __launch_bounds__(256) void k2_hidden_scan(
    const float* __restrict__ spk1,  // [B][G][W]
    const float* __restrict__ wT,    // [W][H]
    const float* __restrict__ hb,    // [H]
    const float* __restrict__ ow,    // [O][H]
    const float* __restrict__ ob,    // [O]
    float* __restrict__ partial,     // [B][16][10]
    int* __restrict__ counter,
    float* __restrict__ out)         // [B][10]
{
    __shared__ __align__(16) char smem[40960];        // sk[20][512] ALIASED with red[8][20][16]x4
    float (*sk)[NW]     = (float (*)[NW])smem;
    f32x4 (*red)[NG][16] = (f32x4 (*)[NG][16])smem;
    __shared__ int lastFlag;

    int bid = blockIdx.x;            // 0..511
    int b = bid >> 4;                // 0..31
    int hgrp = bid & 15;             // 0..15 (64 h per block)
    int t = threadIdx.x;
    int lane4 = t & 15;
    int c = t >> 4;                  // k-chunk 0..15 (32 kk each)
    int h = hgrp * 64 + lane4 * 4;   // h-quad base

    // cooperative stage: 2560 float4 / 256 threads = 10 each, coalesced
    {
        const f32x4* __restrict__ sp4 =
            (const f32x4*)(spk1 + (size_t)b * NG * NW);
        f32x4* sk4 = (f32x4*)smem;
        #pragma unroll
        for (int i = 0; i < 10; ++i)
            sk4[t + i * 256] = sp4[t + i * 256];
    }
    __syncthreads();

    f32x4 acc[NG];
    #pragma unroll
    for (int g = 0; g < NG; ++g)
        #pragma unroll
        for (int j = 0; j < 4; ++j) acc[g][j] = 0.0f;

    int k0 = c * 32;
    #pragma unroll
    for (int kkg = 0; kkg < 8; ++kkg) {
        int kk = k0 + (((kkg + c) & 7) << 2);   // rotated -> bank-conflict-free
        f32x4 w0 = *(const f32x4*)&wT[(kk + 0) * NH + h];
        f32x4 w1 = *(const f32x4*)&wT[(kk + 1) * NH + h];
        f32x4 w2 = *(const f32x4*)&wT[(kk + 2) * NH + h];
        f32x4 w3 = *(const f32x4*)&wT[(kk + 3) * NH + h];
        #pragma unroll
        for (int g = 0; g < NG; ++g) {
            f32x4 u = *(const f32x4*)&sk[g][kk];   // 4 uniq addrs/wave, distinct banks
            #pragma unroll
            for (int j = 0; j < 4; ++j)
                acc[g][j] = fmaf(u[0], w0[j], fmaf(u[1], w1[j],
                            fmaf(u[2], w2[j], fmaf(u[3], w3[j], acc[g][j]))));
        }
    }

    __syncthreads();                 // all sk reads done -> safe to alias as red
    if (c < 8) {
        #pragma unroll
        for (int g = 0; g < NG; ++g) red[c][g][lane4] = acc[g];
    }
    __syncthreads();
    if (c >= 8) {
        #pragma unroll
        for (int g = 0; g < NG; ++g) {
            f32x4 v = red[c - 8][g][lane4];
            #pragma unroll
            for (int j = 0; j < 4; ++j) v[j] += acc[g][j];
            red[c - 8][g][lane4] = v;
        }
    }
    __syncthreads();

    // wave 0: 20-step scan (one h per lane) + folded output-layer dots
    if (t < 64) {
        float hbias = hb[hgrp * 64 + t];
        int hl = t >> 2, hj = t & 3;
        float mem = 0.0f;
        #pragma unroll
        for (int g = 0; g < NG; ++g) {
            float xin = hbias;
            #pragma unroll
            for (int cc = 0; cc < 8; ++cc) xin += red[cc][g][hl][hj];
            float base = fmaf(BETA, mem, xin);
            mem = (mem > THRESH) ? 0.0f : base;
        }
        float spike = (mem > THRESH) ? 1.0f : 0.0f;

        #pragma unroll
        for (int o = 0; o < NO; ++o) {
            float p = spike * ow[o * NH + hgrp * 64 + t];
            p += __shfl_down(p, 32);
            p += __shfl_down(p, 16);
            p += __shfl_down(p, 8);
            p += __shfl_down(p, 4);
            p += __shfl_down(p, 2);
            p += __shfl_down(p, 1);
            if (t == 0) partial[(b * 16 + hgrp) * NO + o] = p;  // all stores by t0
        }
    }

    // last-block reduction + softmax (single-thread release: t0 stored all partials)
    if (t == 0) {
        __threadfence();
        int old = atomicAdd(counter, 1);
        lastFlag = (old == NB * 16 - 1);
    }
    __syncthreads();
    if (lastFlag) {
        __threadfence();
        if (t < NB) {
            const float* p = partial + t * 16 * NO;
            float v[NO];
            #pragma unroll
            for (int o = 0; o < NO; ++o) v[o] = ob[o];
            #pragma unroll
            for (int hg = 0; hg < 16; ++hg)
                #pragma unroll
                for (int o = 0; o < NO; ++o) v[o] += p[hg * NO + o];

            float mx = -1e30f;
            #pragma unroll
            for (int o = 0; o < NO; ++o) mx = fmaxf(mx, v[o]);
            float sum = 0.0f;
            #pragma unroll
            for (int o = 0; o < NO; ++o) { v[o] = expf(v[o] - mx); sum += v[o]; }
            float inv = 1.0f / sum;
            #pragma unroll
            for (int o = 0; o < NO; ++o) out[t * NO + o] = v[o] * inv;
        }
    }
}

extern "C" void kernel_launch(void* const* d_in, const int* in_sizes, int n_in,
                              void* d_out, int out_size, void* d_ws, size_t ws_size,
                              hipStream_t stream) {
    const f32x4*  x  = (const f32x4*)d_in[0];   // [32][2000][512][4]
    const float*  cw = (const float*)d_in[1];   // [4]
    const float*  cb = (const float*)d_in[2];   // [1]
    const float*  hw = (const float*)d_in[3];   // [1024][512]
    const float*  hb = (const float*)d_in[4];   // [1024]
    const float*  ow = (const float*)d_in[5];   // [10][1024]
    const float*  ob = (const float*)d_in[6];   // [10]
    float* out = (float*)d_out;                 // [32][10]

    char* ws = (char*)d_ws;
    float* spk1    = (float*)(ws);                        // 32*20*512*4 = 1,310,720 B
    float* wT      = (float*)(ws + 1310720);              // 512*1024*4  = 2,097,152 B
    float* partial = (float*)(ws + 1310720 + 2097152);    // 32*16*10*4  =    20,480 B
    int*   counter = (int*)(ws + 1310720 + 2097152 + 20480);

    // stage 1: conv + scan1 (~78us, HBM roofline) fused with weight transpose
    k1_conv_scan_tr<<<1792, 256, 0, stream>>>(x, cw, cb, spk1, hw, wT, counter);

    // stage 2+3+4: hidden GEMM (h-quad, 2 blocks/CU, aliased LDS) + scan2
    //              + output dots + last-block softmax
    k2_hidden_scan<<<NB * 16, 256, 0, stream>>>(spk1, wT, hb, ow, ob,
                                                partial, counter, out);
}